// Round 6
// baseline (117.343 us; speedup 1.0000x reference)
//
#include <hip/hip_runtime.h>
#include <math.h>

#define DHID   784
#define HID    1024
#define NB     10
#define MC_LD  800                         // padded leading dim for Mc rows
#define M2_OFF (11*MC_LD)                  // 8800
#define M2_LD  13
#define C0_OFF (M2_OFF + 64*M2_LD)         // 9632
#define WS_FLOATS 9648
#define DELTA0 7.0f

// ---------------------------------------------------------------------------
// ROUND 6: org-B main. Dot split across ALL 64 lanes (no subgroup broadcast
// redundancy): LDS b128 instrs drop 4x (every read returns 1KB unique data).
// 4 rows/wave, 16 rows/block, 1024 blocks -> 4 blk/CU, 16 waves/CU.
// Launches: prep, main_B x3  =>  main_B = (dur - 5.78 - prep)/3.
// ---------------------------------------------------------------------------

// prep: fold all weights (unchanged). ws layout (floats):
//   [0 .. 8800)   Mc[11][800]: c<10 -> col c of M1 = W_in @ (g .* W_out)
//                              c==10 -> w_mean[d] = (1/1024) * sum_j W_in[d][j]
//   [8800..9632)  M2[64][13] : M2[h][c] = sum_j W_ph[h][j]*g[j]*W_out[j][c]
//   [9632..9642)  c0[10] = (b_in+b_ph)*g @ W_out + b_out
//   [9642]        bmean = mean(b_in)
// g[j] = 2 if j<5 else 1 (spiking gains provably constant).
__global__ __launch_bounds__(256) void prep_kernel(
    const float* __restrict__ W_in,  const float* __restrict__ b_in,
    const float* __restrict__ W_ph,  const float* __restrict__ b_ph,
    const float* __restrict__ W_out, const float* __restrict__ b_out,
    float* __restrict__ ws) {
  __shared__ float wlds[HID * 11];           // 44 KB
  const int tid = threadIdx.x;

  for (int idx = tid; idx < HID * NB; idx += 256) {
    const int j = idx / NB;
    const int c = idx - j * NB;
    wlds[j * 11 + c] = W_out[idx];
  }
  __syncthreads();

  const int w = tid >> 6;
  const int l = tid & 63;
  const int b = blockIdx.x * 4 + w;
  if (b > DHID + 64) return;

  float acc[11];
#pragma unroll
  for (int c = 0; c < 11; ++c) acc[c] = 0.f;

#pragma unroll 4
  for (int it = 0; it < 16; ++it) {
    const int j = l + 64 * it;
    float wv, extra;
    if (b < DHID)           { wv = W_in[b * HID + j];          extra = wv;      }
    else if (b < DHID + 64) { wv = W_ph[(b - DHID) * HID + j]; extra = 0.f;     }
    else                    { wv = b_in[j] + b_ph[j];          extra = b_in[j]; }
    const float wg = (j < 5) ? 2.0f * wv : wv;
    const float* wr = &wlds[j * 11];
#pragma unroll
    for (int c = 0; c < 10; ++c) acc[c] += wg * wr[c];
    acc[10] += extra;
  }

#pragma unroll
  for (int c = 0; c < 11; ++c) {
    float v = acc[c];
    v += __shfl_xor(v, 1,  64);
    v += __shfl_xor(v, 2,  64);
    v += __shfl_xor(v, 4,  64);
    v += __shfl_xor(v, 8,  64);
    v += __shfl_xor(v, 16, 64);
    v += __shfl_xor(v, 32, 64);
    acc[c] = v;
  }

  if (l == 0) {
    if (b < DHID) {
#pragma unroll
      for (int c = 0; c < 10; ++c) ws[c * MC_LD + b] = acc[c];
      ws[10 * MC_LD + b] = acc[10] * (1.0f / HID);
    } else if (b < DHID + 64) {
      const int h = b - DHID;
#pragma unroll
      for (int c = 0; c < 10; ++c) ws[M2_OFF + h * M2_LD + c] = acc[c];
      ws[M2_OFF + h * M2_LD + 10] = 0.f;
      ws[M2_OFF + h * M2_LD + 11] = 0.f;
      ws[M2_OFF + h * M2_LD + 12] = 0.f;
    } else {
#pragma unroll
      for (int c = 0; c < 10; ++c) ws[C0_OFF + c] = acc[c] + b_out[c];
      ws[C0_OFF + 10] = acc[10] * (1.0f / HID);
    }
  }
}

// ---- main org B: 64-lane dot split, 4 rows/wave, 1024 blocks ---------------
__global__ __launch_bounds__(256) void main_kernel_B(const float* __restrict__ x,
                                                     const float* __restrict__ ws,
                                                     float* __restrict__ out) {
  __shared__ float lds[WS_FLOATS];
  const int tid = threadIdx.x;

  for (int idx = tid; idx < WS_FLOATS / 4; idx += 256)
    ((float4*)lds)[idx] = ((const float4*)ws)[idx];
  __syncthreads();

  const int wav  = tid >> 6;
  const int lane = tid & 63;
  const int row0 = blockIdx.x * 16 + wav * 4;        // 4 rows per wave
  const float* x0 = x + (size_t)row0 * DHID;
  const int d0 = 4 * lane;

  float acc[4][11];
#pragma unroll
  for (int r = 0; r < 4; ++r)
#pragma unroll
    for (int c = 0; c < 11; ++c) acc[r][c] = 0.f;

#pragma unroll
  for (int i = 0; i < 3; ++i) {
    const int d = d0 + 256 * i;                      // 64 lanes cover 256 floats
    float4 xv[4];
#pragma unroll
    for (int r = 0; r < 4; ++r)
      xv[r] = *(const float4*)(x0 + (size_t)r * DHID + d);
#pragma unroll
    for (int c = 0; c < 11; ++c) {
      const float4 mv = *(const float4*)(&lds[c * MC_LD + d]);
#pragma unroll
      for (int r = 0; r < 4; ++r)
        acc[r][c] += xv[r].x * mv.x + xv[r].y * mv.y +
                     xv[r].z * mv.z + xv[r].w * mv.w;
    }
  }
  if (lane < 4) {                                    // tail: d = 768..783
    const int d = 768 + 4 * lane;
    float4 xv[4];
#pragma unroll
    for (int r = 0; r < 4; ++r)
      xv[r] = *(const float4*)(x0 + (size_t)r * DHID + d);
#pragma unroll
    for (int c = 0; c < 11; ++c) {
      const float4 mv = *(const float4*)(&lds[c * MC_LD + d]);
#pragma unroll
      for (int r = 0; r < 4; ++r)
        acc[r][c] += xv[r].x * mv.x + xv[r].y * mv.y +
                     xv[r].z * mv.z + xv[r].w * mv.w;
    }
  }

  // full 64-lane butterfly reduce; result replicated in all lanes
#pragma unroll
  for (int r = 0; r < 4; ++r)
#pragma unroll
    for (int c = 0; c < 11; ++c) {
      float v = acc[r][c];
      v += __shfl_xor(v, 1,  64);
      v += __shfl_xor(v, 2,  64);
      v += __shfl_xor(v, 4,  64);
      v += __shfl_xor(v, 8,  64);
      v += __shfl_xor(v, 16, 64);
      v += __shfl_xor(v, 32, 64);
      acc[r][c] = v;
    }

  // phasor tail: half-wave per row pair; lane (h = lane&31) owns harmonic h+1
  const float bmean = lds[C0_OFF + 10];
  const int  half = lane >> 5;                       // 0 -> rows 0,1; 1 -> rows 2,3
  const int  h    = lane & 31;
  float m2cos[10], m2sin[10];
#pragma unroll
  for (int c = 0; c < 10; ++c) {
    m2cos[c] = lds[M2_OFF + h * M2_LD + c];          // stride 13: conflict-free
    m2sin[c] = lds[M2_OFF + (h + 32) * M2_LD + c];
  }
#pragma unroll
  for (int rr = 0; rr < 2; ++rr) {
    const int r = half * 2 + rr;
    const float base = DELTA0 * (acc[r][10] + bmean);
    float s, cph;
    __sincosf((float)(h + 1) * base, &s, &cph);
    float t[10];
#pragma unroll
    for (int c = 0; c < 10; ++c) t[c] = cph * m2cos[c] + s * m2sin[c];
#pragma unroll
    for (int c = 0; c < 10; ++c) {                   // 32-lane reduce (xor<32 stays in half)
      float v = t[c];
      v += __shfl_xor(v, 1,  64);
      v += __shfl_xor(v, 2,  64);
      v += __shfl_xor(v, 4,  64);
      v += __shfl_xor(v, 8,  64);
      v += __shfl_xor(v, 16, 64);
      t[c] = v;
    }
    if (h == 0) {
#pragma unroll
      for (int c = 0; c < 10; ++c)
        out[(row0 + r) * NB + c] = acc[r][c] + t[c] + lds[C0_OFF + c];
    }
  }
}

// ---------------------------------------------------------------------------
extern "C" void kernel_launch(void* const* d_in, const int* in_sizes, int n_in,
                              void* d_out, int out_size, void* d_ws, size_t ws_size,
                              hipStream_t stream) {
  const float* x     = (const float*)d_in[0];
  const float* W_in  = (const float*)d_in[1];
  const float* b_in  = (const float*)d_in[2];
  const float* W_ph  = (const float*)d_in[3];
  const float* b_ph  = (const float*)d_in[4];
  const float* W_out = (const float*)d_in[5];
  const float* b_out = (const float*)d_in[6];
  float* out = (float*)d_out;
  float* ws  = (float*)d_ws;

  // dur6 = ovh(5.78) + prep + 3*main_B
  prep_kernel<<<(DHID + 64 + 1 + 3) / 4, 256, 0, stream>>>(W_in, b_in, W_ph, b_ph,
                                                           W_out, b_out, ws);
  main_kernel_B<<<1024, 256, 0, stream>>>(x, ws, out);
  main_kernel_B<<<1024, 256, 0, stream>>>(x, ws, out);
  main_kernel_B<<<1024, 256, 0, stream>>>(x, ws, out);
}

// Round 7
// 55.071 us; speedup vs baseline: 2.1308x; 2.1308x over previous
//
#include <hip/hip_runtime.h>
#include <math.h>

#define DHID   784
#define HID    1024
#define NB     10
#define MC_LD  800                         // padded leading dim for Mc rows
#define M2_OFF (11*MC_LD)                  // 8800
#define M2_LD  20                          // 16B-aligned rows; 2-way banks only
#define C0_OFF (M2_OFF + 64*M2_LD)         // 10080
#define WS_FLOATS 10096                    // 2524 float4
#define DELTA0 7.0f

typedef float v2f __attribute__((ext_vector_type(2)));
typedef float v4f __attribute__((ext_vector_type(4)));

// DPP rotate-add: 16-lane allreduce on the VALU pipe (no LDS traffic).
template <int CTRL>
__device__ __forceinline__ float dpp_add(float v) {
  int t = __builtin_amdgcn_update_dpp(0, __float_as_int(v), CTRL, 0xF, 0xF, false);
  return v + __int_as_float(t);
}
__device__ __forceinline__ float red16(float v) {
  v = dpp_add<0x121>(v);   // row_ror:1
  v = dpp_add<0x122>(v);   // row_ror:2
  v = dpp_add<0x124>(v);   // row_ror:4
  v = dpp_add<0x128>(v);   // row_ror:8
  return v;                // every lane holds its 16-lane-row total
}

// ---------------------------------------------------------------------------
// prep: fold all weights. ws layout (floats):
//   [0 .. 8800)    Mc[11][800]: c<10 -> col c of M1 = W_in @ (g .* W_out)
//                               c==10 -> w_mean[d] = (1/1024)*sum_j W_in[d][j]
//   [8800..10080)  M2[64][20]: M2[h][c] = sum_j W_ph[h][j]*g[j]*W_out[j][c]
//   [10080..10090) c0[10] = (b_in+b_ph)*g @ W_out + b_out
//   [10090]        bmean = mean(b_in)
// g[j] = 2 if j<5 else 1 (spiking gains provably constant: every top-k token
// spikes exactly once and resets to 0 -> V all-zero -> top_k picks 0..4).
// ---------------------------------------------------------------------------
__global__ __launch_bounds__(256) void prep_kernel(
    const float* __restrict__ W_in,  const float* __restrict__ b_in,
    const float* __restrict__ W_ph,  const float* __restrict__ b_ph,
    const float* __restrict__ W_out, const float* __restrict__ b_out,
    float* __restrict__ ws) {
  __shared__ float wlds[HID * 11];           // 44 KB
  const int tid = threadIdx.x;

  for (int idx = tid; idx < HID * NB; idx += 256) {
    const int j = idx / NB;
    const int c = idx - j * NB;
    wlds[j * 11 + c] = W_out[idx];
  }
  __syncthreads();

  const int w = tid >> 6;
  const int l = tid & 63;
  const int b = blockIdx.x * 4 + w;          // 0..783 W_in; 784..847 W_ph; 848 bias
  if (b > DHID + 64) return;

  float acc[11];
#pragma unroll
  for (int c = 0; c < 11; ++c) acc[c] = 0.f;

#pragma unroll 4
  for (int it = 0; it < 16; ++it) {
    const int j = l + 64 * it;
    float wv, extra;
    if (b < DHID)           { wv = W_in[b * HID + j];          extra = wv;      }
    else if (b < DHID + 64) { wv = W_ph[(b - DHID) * HID + j]; extra = 0.f;     }
    else                    { wv = b_in[j] + b_ph[j];          extra = b_in[j]; }
    const float wg = (j < 5) ? 2.0f * wv : wv;
    const float* wr = &wlds[j * 11];
#pragma unroll
    for (int c = 0; c < 10; ++c) acc[c] += wg * wr[c];
    acc[10] += extra;
  }

#pragma unroll
  for (int c = 0; c < 11; ++c) {
    float v = acc[c];
    v += __shfl_xor(v, 1,  64);
    v += __shfl_xor(v, 2,  64);
    v += __shfl_xor(v, 4,  64);
    v += __shfl_xor(v, 8,  64);
    v += __shfl_xor(v, 16, 64);
    v += __shfl_xor(v, 32, 64);
    acc[c] = v;
  }

  if (l == 0) {
    if (b < DHID) {
#pragma unroll
      for (int c = 0; c < 10; ++c) ws[c * MC_LD + b] = acc[c];
      ws[10 * MC_LD + b] = acc[10] * (1.0f / HID);
    } else if (b < DHID + 64) {
      const int h = b - DHID;
#pragma unroll
      for (int c = 0; c < 10; ++c) ws[M2_OFF + h * M2_LD + c] = acc[c];
    } else {
#pragma unroll
      for (int c = 0; c < 10; ++c) ws[C0_OFF + c] = acc[c] + b_out[c];
      ws[C0_OFF + 10] = acc[10] * (1.0f / HID);
    }
  }
}

// ---------------------------------------------------------------------------
// main_D: main_N skeleton (8 rows/wave: 4 k-groups x 16 lanes x 2 rows,
// 512 blocks) + DPP reductions (zero LDS-pipe reduce) + packed-f32 dots
// + M2 hoisted to registers + coalesced select-chain stores.
// ---------------------------------------------------------------------------
__global__ __launch_bounds__(256, 2) void main_kernel_D(
    const float* __restrict__ x, const float* __restrict__ ws,
    float* __restrict__ out) {
  __shared__ __align__(16) float lds[WS_FLOATS];
  const int tid = threadIdx.x;

  for (int idx = tid; idx < WS_FLOATS / 4; idx += 256)
    ((v4f*)lds)[idx] = ((const v4f*)ws)[idx];
  __syncthreads();

  const int wav  = tid >> 6;
  const int lane = tid & 63;
  const int kl   = lane & 15;
  const int rsub = lane >> 4;
  const int row  = blockIdx.x * 32 + wav * 8 + rsub * 2;   // 2 rows per lane
  const float* x0 = x + (size_t)row * DHID;
  const int d0 = 4 * kl;

  v2f acc0[11], acc1[11];
#pragma unroll
  for (int c = 0; c < 11; ++c) { acc0[c] = (v2f)0.f; acc1[c] = (v2f)0.f; }

  v4f xa = *(const v4f*)(x0 + d0);
  v4f xb = *(const v4f*)(x0 + DHID + d0);

  for (int i = 0; i < 12; ++i) {
    v4f na, nb;
    if (i < 11) {                        // 1-deep prefetch of next x pair
      const int dn = d0 + 64 * (i + 1);
      na = *(const v4f*)(x0 + dn);
      nb = *(const v4f*)(x0 + DHID + dn);
    }
    const int d = d0 + 64 * i;
#pragma unroll
    for (int c = 0; c < 11; ++c) {
      const v4f mv = *(const v4f*)(&lds[c * MC_LD + d]);
      acc0[c] += xa.lo * mv.lo;  acc0[c] += xa.hi * mv.hi;   // v_pk_fma_f32
      acc1[c] += xb.lo * mv.lo;  acc1[c] += xb.hi * mv.hi;
    }
    xa = na; xb = nb;
  }
  if (kl < 4) {                          // tail: d = 768 + 4*kl < 784
    const int d = 768 + 4 * kl;
    const v4f ta = *(const v4f*)(x0 + d);
    const v4f tb = *(const v4f*)(x0 + DHID + d);
#pragma unroll
    for (int c = 0; c < 11; ++c) {
      const v4f mv = *(const v4f*)(&lds[c * MC_LD + d]);
      acc0[c] += ta.lo * mv.lo;  acc0[c] += ta.hi * mv.hi;
      acc1[c] += tb.lo * mv.lo;  acc1[c] += tb.hi * mv.hi;
    }
  }

  // hoist this lane's 4 M2 rows into registers (reused by both output rows)
  float mA[10], mB[10], mC[10], mD[10];
  {
    const float* p;
    p = &lds[M2_OFF + (kl)      * M2_LD];
    *(v4f*)&mA[0] = *(const v4f*)p;  *(v4f*)&mA[4] = *(const v4f*)(p + 4);
    *(v2f*)&mA[8] = *(const v2f*)(p + 8);
    p = &lds[M2_OFF + (kl + 16) * M2_LD];
    *(v4f*)&mB[0] = *(const v4f*)p;  *(v4f*)&mB[4] = *(const v4f*)(p + 4);
    *(v2f*)&mB[8] = *(const v2f*)(p + 8);
    p = &lds[M2_OFF + (kl + 32) * M2_LD];
    *(v4f*)&mC[0] = *(const v4f*)p;  *(v4f*)&mC[4] = *(const v4f*)(p + 4);
    *(v2f*)&mC[8] = *(const v2f*)(p + 8);
    p = &lds[M2_OFF + (kl + 48) * M2_LD];
    *(v4f*)&mD[0] = *(const v4f*)p;  *(v4f*)&mD[4] = *(const v4f*)(p + 4);
    *(v2f*)&mD[8] = *(const v2f*)(p + 8);
  }

  // horizontal + DPP 16-lane allreduce (VALU only)
  float s0[11], s1[11];
#pragma unroll
  for (int c = 0; c < 11; ++c) {
    s0[c] = red16(acc0[c].x + acc0[c].y);
    s1[c] = red16(acc1[c].x + acc1[c].y);
  }

  // phasor tail: lane kl owns harmonics kl+1 (A:cos,C:sin) and kl+17 (B,D)
  const float bmean = lds[C0_OFF + 10];
  const float base0 = DELTA0 * (s0[10] + bmean);
  const float base1 = DELTA0 * (s1[10] + bmean);
  float sA0, cA0, sB0, cB0, sA1, cA1, sB1, cB1;
  __sincosf((float)(kl + 1)  * base0, &sA0, &cA0);
  __sincosf((float)(kl + 17) * base0, &sB0, &cB0);
  __sincosf((float)(kl + 1)  * base1, &sA1, &cA1);
  __sincosf((float)(kl + 17) * base1, &sB1, &cB1);

  float t0[10], t1[10];
#pragma unroll
  for (int c = 0; c < 10; ++c) {
    t0[c] = red16(cA0 * mA[c] + cB0 * mB[c] + sA0 * mC[c] + sB0 * mD[c]);
    t1[c] = red16(cA1 * mA[c] + cB1 * mB[c] + sA1 * mC[c] + sB1 * mD[c]);
  }

  // lane kl (<10) emits element kl of each row: select-chain keeps regs static
  const float c0v = lds[C0_OFF + (kl < 10 ? kl : 0)];
  float o0 = 0.f, o1 = 0.f;
#pragma unroll
  for (int c = 0; c < 10; ++c) {
    o0 = (kl == c) ? s0[c] + t0[c] : o0;
    o1 = (kl == c) ? s1[c] + t1[c] : o1;
  }
  if (kl < 10) {
    out[(size_t)row * NB + kl]       = o0 + c0v;
    out[(size_t)(row + 1) * NB + kl] = o1 + c0v;
  }
}

// ---------------------------------------------------------------------------
extern "C" void kernel_launch(void* const* d_in, const int* in_sizes, int n_in,
                              void* d_out, int out_size, void* d_ws, size_t ws_size,
                              hipStream_t stream) {
  const float* x     = (const float*)d_in[0];
  const float* W_in  = (const float*)d_in[1];
  const float* b_in  = (const float*)d_in[2];
  const float* W_ph  = (const float*)d_in[3];
  const float* b_ph  = (const float*)d_in[4];
  const float* W_out = (const float*)d_in[5];
  const float* b_out = (const float*)d_in[6];
  float* out = (float*)d_out;
  float* ws  = (float*)d_ws;

  // dur7 = ovh(5.78) + prep + 3*main_D
  prep_kernel<<<(DHID + 64 + 1 + 3) / 4, 256, 0, stream>>>(W_in, b_in, W_ph, b_ph,
                                                           W_out, b_out, ws);
  main_kernel_D<<<512, 256, 0, stream>>>(x, ws, out);
  main_kernel_D<<<512, 256, 0, stream>>>(x, ws, out);
  main_kernel_D<<<512, 256, 0, stream>>>(x, ws, out);
}

// Round 8
// 54.094 us; speedup vs baseline: 2.1693x; 1.0181x over previous
//
#include <hip/hip_runtime.h>
#include <math.h>

#define DHID   784
#define HID    1024
#define NB     10
#define MC_LD  800                         // padded leading dim for Mc rows
#define M2_OFF (11*MC_LD)                  // 8800
#define M2_LD  20                          // 16B-aligned rows; 2-way banks only
#define C0_OFF (M2_OFF + 64*M2_LD)         // 10080
#define WS_FLOATS 10096                    // 2524 float4
#define DELTA0 7.0f

typedef float v2f __attribute__((ext_vector_type(2)));
typedef float v4f __attribute__((ext_vector_type(4)));

// DPP rotate-add: 16-lane allreduce on the VALU pipe (no LDS traffic).
template <int CTRL>
__device__ __forceinline__ float dpp_add(float v) {
  int t = __builtin_amdgcn_update_dpp(0, __float_as_int(v), CTRL, 0xF, 0xF, false);
  return v + __int_as_float(t);
}
__device__ __forceinline__ float red16(float v) {
  v = dpp_add<0x121>(v);   // row_ror:1
  v = dpp_add<0x122>(v);   // row_ror:2
  v = dpp_add<0x124>(v);   // row_ror:4
  v = dpp_add<0x128>(v);   // row_ror:8
  return v;                // every lane holds its 16-lane-row total
}

// ---------------------------------------------------------------------------
// prep: fold all weights (unchanged). ws layout (floats):
//   [0 .. 8800)    Mc[11][800]: c<10 -> col c of M1 = W_in @ (g .* W_out)
//                               c==10 -> w_mean[d] = (1/1024)*sum_j W_in[d][j]
//   [8800..10080)  M2[64][20]: M2[h][c] = sum_j W_ph[h][j]*g[j]*W_out[j][c]
//   [10080..10090) c0[10] = (b_in+b_ph)*g @ W_out + b_out
//   [10090]        bmean = mean(b_in)
// g[j] = 2 if j<5 else 1 (spiking gains provably constant).
// ---------------------------------------------------------------------------
__global__ __launch_bounds__(256) void prep_kernel(
    const float* __restrict__ W_in,  const float* __restrict__ b_in,
    const float* __restrict__ W_ph,  const float* __restrict__ b_ph,
    const float* __restrict__ W_out, const float* __restrict__ b_out,
    float* __restrict__ ws) {
  __shared__ float wlds[HID * 11];           // 44 KB
  const int tid = threadIdx.x;

  for (int idx = tid; idx < HID * NB; idx += 256) {
    const int j = idx / NB;
    const int c = idx - j * NB;
    wlds[j * 11 + c] = W_out[idx];
  }
  __syncthreads();

  const int w = tid >> 6;
  const int l = tid & 63;
  const int b = blockIdx.x * 4 + w;          // 0..783 W_in; 784..847 W_ph; 848 bias
  if (b > DHID + 64) return;

  float acc[11];
#pragma unroll
  for (int c = 0; c < 11; ++c) acc[c] = 0.f;

#pragma unroll 4
  for (int it = 0; it < 16; ++it) {
    const int j = l + 64 * it;
    float wv, extra;
    if (b < DHID)           { wv = W_in[b * HID + j];          extra = wv;      }
    else if (b < DHID + 64) { wv = W_ph[(b - DHID) * HID + j]; extra = 0.f;     }
    else                    { wv = b_in[j] + b_ph[j];          extra = b_in[j]; }
    const float wg = (j < 5) ? 2.0f * wv : wv;
    const float* wr = &wlds[j * 11];
#pragma unroll
    for (int c = 0; c < 10; ++c) acc[c] += wg * wr[c];
    acc[10] += extra;
  }

#pragma unroll
  for (int c = 0; c < 11; ++c) {
    float v = acc[c];
    v += __shfl_xor(v, 1,  64);
    v += __shfl_xor(v, 2,  64);
    v += __shfl_xor(v, 4,  64);
    v += __shfl_xor(v, 8,  64);
    v += __shfl_xor(v, 16, 64);
    v += __shfl_xor(v, 32, 64);
    acc[c] = v;
  }

  if (l == 0) {
    if (b < DHID) {
#pragma unroll
      for (int c = 0; c < 10; ++c) ws[c * MC_LD + b] = acc[c];
      ws[10 * MC_LD + b] = acc[10] * (1.0f / HID);
    } else if (b < DHID + 64) {
      const int h = b - DHID;
#pragma unroll
      for (int c = 0; c < 10; ++c) ws[M2_OFF + h * M2_LD + c] = acc[c];
    } else {
#pragma unroll
      for (int c = 0; c < 10; ++c) ws[C0_OFF + c] = acc[c] + b_out[c];
      ws[C0_OFF + 10] = acc[10] * (1.0f / HID);
    }
  }
}

// ---------------------------------------------------------------------------
// main_G = round-7 main_D + 3-deep x prefetch (4-slot register ring).
// Single-variable experiment: outstanding loads/wave 2 -> 6-8 (2-8 KB in
// flight) to break the closed-loop MLP limit (period ~3000 cyc -> BW-bound).
// ---------------------------------------------------------------------------
__global__ __launch_bounds__(256, 2) void main_kernel_G(
    const float* __restrict__ x, const float* __restrict__ ws,
    float* __restrict__ out) {
  __shared__ __align__(16) float lds[WS_FLOATS];
  const int tid = threadIdx.x;

  for (int idx = tid; idx < WS_FLOATS / 4; idx += 256)
    ((v4f*)lds)[idx] = ((const v4f*)ws)[idx];
  __syncthreads();

  const int wav  = tid >> 6;
  const int lane = tid & 63;
  const int kl   = lane & 15;
  const int rsub = lane >> 4;
  const int row  = blockIdx.x * 32 + wav * 8 + rsub * 2;   // 2 rows per lane
  const float* x0 = x + (size_t)row * DHID;
  const int d0 = 4 * kl;

  v2f acc0[11], acc1[11];
#pragma unroll
  for (int c = 0; c < 11; ++c) { acc0[c] = (v2f)0.f; acc1[c] = (v2f)0.f; }

  // 4-slot prefetch ring; prologue fills slots 0..2 and the tail pair
  v4f sa[4], sb[4];
#pragma unroll
  for (int i = 0; i < 3; ++i) {
    sa[i] = *(const v4f*)(x0 + d0 + 64 * i);
    sb[i] = *(const v4f*)(x0 + DHID + d0 + 64 * i);
  }
  v4f ta, tb;
  if (kl < 4) {
    ta = *(const v4f*)(x0 + 768 + 4 * kl);
    tb = *(const v4f*)(x0 + DHID + 768 + 4 * kl);
  }

#pragma unroll
  for (int i = 0; i < 12; ++i) {
    if (i + 3 < 12) {                       // keep 3 iterations in flight
      const int dn = d0 + 64 * (i + 3);
      sa[(i + 3) & 3] = *(const v4f*)(x0 + dn);
      sb[(i + 3) & 3] = *(const v4f*)(x0 + DHID + dn);
    }
    const v4f xa = sa[i & 3];
    const v4f xb = sb[i & 3];
    const int d = d0 + 64 * i;
#pragma unroll
    for (int c = 0; c < 11; ++c) {
      const v4f mv = *(const v4f*)(&lds[c * MC_LD + d]);
      acc0[c] += xa.lo * mv.lo;  acc0[c] += xa.hi * mv.hi;   // v_pk_fma_f32
      acc1[c] += xb.lo * mv.lo;  acc1[c] += xb.hi * mv.hi;
    }
  }
  if (kl < 4) {                             // tail: d = 768 + 4*kl < 784
    const int d = 768 + 4 * kl;
#pragma unroll
    for (int c = 0; c < 11; ++c) {
      const v4f mv = *(const v4f*)(&lds[c * MC_LD + d]);
      acc0[c] += ta.lo * mv.lo;  acc0[c] += ta.hi * mv.hi;
      acc1[c] += tb.lo * mv.lo;  acc1[c] += tb.hi * mv.hi;
    }
  }

  // hoist this lane's 4 M2 rows into registers (x slots dead by now)
  float mA[10], mB[10], mC[10], mD[10];
  {
    const float* p;
    p = &lds[M2_OFF + (kl)      * M2_LD];
    *(v4f*)&mA[0] = *(const v4f*)p;  *(v4f*)&mA[4] = *(const v4f*)(p + 4);
    *(v2f*)&mA[8] = *(const v2f*)(p + 8);
    p = &lds[M2_OFF + (kl + 16) * M2_LD];
    *(v4f*)&mB[0] = *(const v4f*)p;  *(v4f*)&mB[4] = *(const v4f*)(p + 4);
    *(v2f*)&mB[8] = *(const v2f*)(p + 8);
    p = &lds[M2_OFF + (kl + 32) * M2_LD];
    *(v4f*)&mC[0] = *(const v4f*)p;  *(v4f*)&mC[4] = *(const v4f*)(p + 4);
    *(v2f*)&mC[8] = *(const v2f*)(p + 8);
    p = &lds[M2_OFF + (kl + 48) * M2_LD];
    *(v4f*)&mD[0] = *(const v4f*)p;  *(v4f*)&mD[4] = *(const v4f*)(p + 4);
    *(v2f*)&mD[8] = *(const v2f*)(p + 8);
  }

  // horizontal + DPP 16-lane allreduce (VALU only)
  float s0[11], s1[11];
#pragma unroll
  for (int c = 0; c < 11; ++c) {
    s0[c] = red16(acc0[c].x + acc0[c].y);
    s1[c] = red16(acc1[c].x + acc1[c].y);
  }

  // phasor tail: lane kl owns harmonics kl+1 (A:cos,C:sin) and kl+17 (B,D)
  const float bmean = lds[C0_OFF + 10];
  const float base0 = DELTA0 * (s0[10] + bmean);
  const float base1 = DELTA0 * (s1[10] + bmean);
  float sA0, cA0, sB0, cB0, sA1, cA1, sB1, cB1;
  __sincosf((float)(kl + 1)  * base0, &sA0, &cA0);
  __sincosf((float)(kl + 17) * base0, &sB0, &cB0);
  __sincosf((float)(kl + 1)  * base1, &sA1, &cA1);
  __sincosf((float)(kl + 17) * base1, &sB1, &cB1);

  float t0[10], t1[10];
#pragma unroll
  for (int c = 0; c < 10; ++c) {
    t0[c] = red16(cA0 * mA[c] + cB0 * mB[c] + sA0 * mC[c] + sB0 * mD[c]);
    t1[c] = red16(cA1 * mA[c] + cB1 * mB[c] + sA1 * mC[c] + sB1 * mD[c]);
  }

  // lane kl (<10) emits element kl of each row: select-chain keeps regs static
  const float c0v = lds[C0_OFF + (kl < 10 ? kl : 0)];
  float o0 = 0.f, o1 = 0.f;
#pragma unroll
  for (int c = 0; c < 10; ++c) {
    o0 = (kl == c) ? s0[c] + t0[c] : o0;
    o1 = (kl == c) ? s1[c] + t1[c] : o1;
  }
  if (kl < 10) {
    out[(size_t)row * NB + kl]       = o0 + c0v;
    out[(size_t)(row + 1) * NB + kl] = o1 + c0v;
  }
}

// ---------------------------------------------------------------------------
extern "C" void kernel_launch(void* const* d_in, const int* in_sizes, int n_in,
                              void* d_out, int out_size, void* d_ws, size_t ws_size,
                              hipStream_t stream) {
  const float* x     = (const float*)d_in[0];
  const float* W_in  = (const float*)d_in[1];
  const float* b_in  = (const float*)d_in[2];
  const float* W_ph  = (const float*)d_in[3];
  const float* b_ph  = (const float*)d_in[4];
  const float* W_out = (const float*)d_in[5];
  const float* b_out = (const float*)d_in[6];
  float* out = (float*)d_out;
  float* ws  = (float*)d_ws;

  // dur8 = ovh(5.78) + prep + 3*main_G   (main_G isolated by differencing)
  prep_kernel<<<(DHID + 64 + 1 + 3) / 4, 256, 0, stream>>>(W_in, b_in, W_ph, b_ph,
                                                           W_out, b_out, ws);
  main_kernel_G<<<512, 256, 0, stream>>>(x, ws, out);
  main_kernel_G<<<512, 256, 0, stream>>>(x, ws, out);
  main_kernel_G<<<512, 256, 0, stream>>>(x, ws, out);
}

// Round 9
// 43.844 us; speedup vs baseline: 2.6764x; 1.2338x over previous
//
#include <hip/hip_runtime.h>
#include <math.h>

#define DHID   784
#define HID    1024
#define NB     10
#define MC_LD  800                         // padded leading dim for Mc rows
#define M2_OFF (11*MC_LD)                  // 8800
#define M2_LD  20                          // 16B-aligned rows; 2-way banks only
#define C0_OFF (M2_OFF + 64*M2_LD)         // 10080
#define WS_FLOATS 10096                    // 2524 float4
#define DELTA0 7.0f

typedef float v2f __attribute__((ext_vector_type(2)));
typedef float v4f __attribute__((ext_vector_type(4)));

// DPP rotate-add: 16-lane allreduce on the VALU pipe (no LDS traffic).
template <int CTRL>
__device__ __forceinline__ float dpp_add(float v) {
  int t = __builtin_amdgcn_update_dpp(0, __float_as_int(v), CTRL, 0xF, 0xF, false);
  return v + __int_as_float(t);
}
__device__ __forceinline__ float red16(float v) {
  v = dpp_add<0x121>(v);   // row_ror:1
  v = dpp_add<0x122>(v);   // row_ror:2
  v = dpp_add<0x124>(v);   // row_ror:4
  v = dpp_add<0x128>(v);   // row_ror:8
  return v;
}

// ---------------------------------------------------------------------------
// prep: fold all weights (unchanged). ws layout (floats):
//   [0 .. 8800)    Mc[11][800]; [8800..10080) M2[64][20];
//   [10080..10090) c0[10]; [10090] bmean.
// g[j] = 2 if j<5 else 1 (spiking gains provably constant).
// ---------------------------------------------------------------------------
__global__ __launch_bounds__(256) void prep_kernel(
    const float* __restrict__ W_in,  const float* __restrict__ b_in,
    const float* __restrict__ W_ph,  const float* __restrict__ b_ph,
    const float* __restrict__ W_out, const float* __restrict__ b_out,
    float* __restrict__ ws) {
  __shared__ float wlds[HID * 11];           // 44 KB
  const int tid = threadIdx.x;

  for (int idx = tid; idx < HID * NB; idx += 256) {
    const int j = idx / NB;
    const int c = idx - j * NB;
    wlds[j * 11 + c] = W_out[idx];
  }
  __syncthreads();

  const int w = tid >> 6;
  const int l = tid & 63;
  const int b = blockIdx.x * 4 + w;          // 0..783 W_in; 784..847 W_ph; 848 bias
  if (b > DHID + 64) return;

  float acc[11];
#pragma unroll
  for (int c = 0; c < 11; ++c) acc[c] = 0.f;

#pragma unroll 4
  for (int it = 0; it < 16; ++it) {
    const int j = l + 64 * it;
    float wv, extra;
    if (b < DHID)           { wv = W_in[b * HID + j];          extra = wv;      }
    else if (b < DHID + 64) { wv = W_ph[(b - DHID) * HID + j]; extra = 0.f;     }
    else                    { wv = b_in[j] + b_ph[j];          extra = b_in[j]; }
    const float wg = (j < 5) ? 2.0f * wv : wv;
    const float* wr = &wlds[j * 11];
#pragma unroll
    for (int c = 0; c < 10; ++c) acc[c] += wg * wr[c];
    acc[10] += extra;
  }

#pragma unroll
  for (int c = 0; c < 11; ++c) {
    float v = acc[c];
    v += __shfl_xor(v, 1,  64);
    v += __shfl_xor(v, 2,  64);
    v += __shfl_xor(v, 4,  64);
    v += __shfl_xor(v, 8,  64);
    v += __shfl_xor(v, 16, 64);
    v += __shfl_xor(v, 32, 64);
    acc[c] = v;
  }

  if (l == 0) {
    if (b < DHID) {
#pragma unroll
      for (int c = 0; c < 10; ++c) ws[c * MC_LD + b] = acc[c];
      ws[10 * MC_LD + b] = acc[10] * (1.0f / HID);
    } else if (b < DHID + 64) {
      const int h = b - DHID;
#pragma unroll
      for (int c = 0; c < 10; ++c) ws[M2_OFF + h * M2_LD + c] = acc[c];
    } else {
#pragma unroll
      for (int c = 0; c < 10; ++c) ws[C0_OFF + c] = acc[c] + b_out[c];
      ws[C0_OFF + 10] = acc[10] * (1.0f / HID);
    }
  }
}

// ---------------------------------------------------------------------------
// main_G: unchanged from round 8 (production candidate).
// ---------------------------------------------------------------------------
__global__ __launch_bounds__(256, 2) void main_kernel_G(
    const float* __restrict__ x, const float* __restrict__ ws,
    float* __restrict__ out) {
  __shared__ __align__(16) float lds[WS_FLOATS];
  const int tid = threadIdx.x;

  for (int idx = tid; idx < WS_FLOATS / 4; idx += 256)
    ((v4f*)lds)[idx] = ((const v4f*)ws)[idx];
  __syncthreads();

  const int wav  = tid >> 6;
  const int lane = tid & 63;
  const int kl   = lane & 15;
  const int rsub = lane >> 4;
  const int row  = blockIdx.x * 32 + wav * 8 + rsub * 2;
  const float* x0 = x + (size_t)row * DHID;
  const int d0 = 4 * kl;

  v2f acc0[11], acc1[11];
#pragma unroll
  for (int c = 0; c < 11; ++c) { acc0[c] = (v2f)0.f; acc1[c] = (v2f)0.f; }

  v4f sa[4], sb[4];
#pragma unroll
  for (int i = 0; i < 3; ++i) {
    sa[i] = *(const v4f*)(x0 + d0 + 64 * i);
    sb[i] = *(const v4f*)(x0 + DHID + d0 + 64 * i);
  }
  v4f ta, tb;
  if (kl < 4) {
    ta = *(const v4f*)(x0 + 768 + 4 * kl);
    tb = *(const v4f*)(x0 + DHID + 768 + 4 * kl);
  }

#pragma unroll
  for (int i = 0; i < 12; ++i) {
    if (i + 3 < 12) {
      const int dn = d0 + 64 * (i + 3);
      sa[(i + 3) & 3] = *(const v4f*)(x0 + dn);
      sb[(i + 3) & 3] = *(const v4f*)(x0 + DHID + dn);
    }
    const v4f xa = sa[i & 3];
    const v4f xb = sb[i & 3];
    const int d = d0 + 64 * i;
#pragma unroll
    for (int c = 0; c < 11; ++c) {
      const v4f mv = *(const v4f*)(&lds[c * MC_LD + d]);
      acc0[c] += xa.lo * mv.lo;  acc0[c] += xa.hi * mv.hi;
      acc1[c] += xb.lo * mv.lo;  acc1[c] += xb.hi * mv.hi;
    }
  }
  if (kl < 4) {
    const int d = 768 + 4 * kl;
#pragma unroll
    for (int c = 0; c < 11; ++c) {
      const v4f mv = *(const v4f*)(&lds[c * MC_LD + d]);
      acc0[c] += ta.lo * mv.lo;  acc0[c] += ta.hi * mv.hi;
      acc1[c] += tb.lo * mv.lo;  acc1[c] += tb.hi * mv.hi;
    }
  }

  float mA[10], mB[10], mC[10], mD[10];
  {
    const float* p;
    p = &lds[M2_OFF + (kl)      * M2_LD];
    *(v4f*)&mA[0] = *(const v4f*)p;  *(v4f*)&mA[4] = *(const v4f*)(p + 4);
    *(v2f*)&mA[8] = *(const v2f*)(p + 8);
    p = &lds[M2_OFF + (kl + 16) * M2_LD];
    *(v4f*)&mB[0] = *(const v4f*)p;  *(v4f*)&mB[4] = *(const v4f*)(p + 4);
    *(v2f*)&mB[8] = *(const v2f*)(p + 8);
    p = &lds[M2_OFF + (kl + 32) * M2_LD];
    *(v4f*)&mC[0] = *(const v4f*)p;  *(v4f*)&mC[4] = *(const v4f*)(p + 4);
    *(v2f*)&mC[8] = *(const v2f*)(p + 8);
    p = &lds[M2_OFF + (kl + 48) * M2_LD];
    *(v4f*)&mD[0] = *(const v4f*)p;  *(v4f*)&mD[4] = *(const v4f*)(p + 4);
    *(v2f*)&mD[8] = *(const v2f*)(p + 8);
  }

  float s0[11], s1[11];
#pragma unroll
  for (int c = 0; c < 11; ++c) {
    s0[c] = red16(acc0[c].x + acc0[c].y);
    s1[c] = red16(acc1[c].x + acc1[c].y);
  }

  const float bmean = lds[C0_OFF + 10];
  const float base0 = DELTA0 * (s0[10] + bmean);
  const float base1 = DELTA0 * (s1[10] + bmean);
  float sA0, cA0, sB0, cB0, sA1, cA1, sB1, cB1;
  __sincosf((float)(kl + 1)  * base0, &sA0, &cA0);
  __sincosf((float)(kl + 17) * base0, &sB0, &cB0);
  __sincosf((float)(kl + 1)  * base1, &sA1, &cA1);
  __sincosf((float)(kl + 17) * base1, &sB1, &cB1);

  float t0[10], t1[10];
#pragma unroll
  for (int c = 0; c < 10; ++c) {
    t0[c] = red16(cA0 * mA[c] + cB0 * mB[c] + sA0 * mC[c] + sB0 * mD[c]);
    t1[c] = red16(cA1 * mA[c] + cB1 * mB[c] + sA1 * mC[c] + sB1 * mD[c]);
  }

  const float c0v = lds[C0_OFF + (kl < 10 ? kl : 0)];
  float o0 = 0.f, o1 = 0.f;
#pragma unroll
  for (int c = 0; c < 10; ++c) {
    o0 = (kl == c) ? s0[c] + t0[c] : o0;
    o1 = (kl == c) ? s1[c] + t1[c] : o1;
  }
  if (kl < 10) {
    out[(size_t)row * NB + kl]       = o0 + c0v;
    out[(size_t)(row + 1) * NB + kl] = o1 + c0v;
  }
}

// ---------------------------------------------------------------------------
// probe_A: main_G's EXACT x addressing, zero LDS/epilogue work, occupancy
// pinned to main's (40KB LDS alloc, launch_bounds(256,2)). Writes nothing.
// ---------------------------------------------------------------------------
__global__ __launch_bounds__(256, 2) void probe_pattern(
    const float* __restrict__ x) {
  __shared__ float pad[WS_FLOATS];                 // occupancy pin (~40 KB)
  const int tid = threadIdx.x;
  ((volatile float*)pad)[tid] = 0.f;               // keep allocation alive

  const int wav  = tid >> 6;
  const int lane = tid & 63;
  const int kl   = lane & 15;
  const int rsub = lane >> 4;
  const int row  = blockIdx.x * 32 + wav * 8 + rsub * 2;
  const float* x0 = x + (size_t)row * DHID;
  const int d0 = 4 * kl;

  v4f sa[4], sb[4];
#pragma unroll
  for (int i = 0; i < 3; ++i) {
    sa[i] = *(const v4f*)(x0 + d0 + 64 * i);
    sb[i] = *(const v4f*)(x0 + DHID + d0 + 64 * i);
  }
  v4f ta = (v4f)0.f, tb = (v4f)0.f;
  if (kl < 4) {
    ta = *(const v4f*)(x0 + 768 + 4 * kl);
    tb = *(const v4f*)(x0 + DHID + 768 + 4 * kl);
  }

  v4f vs = (v4f)0.f;
#pragma unroll
  for (int i = 0; i < 12; ++i) {
    if (i + 3 < 12) {
      const int dn = d0 + 64 * (i + 3);
      sa[(i + 3) & 3] = *(const v4f*)(x0 + dn);
      sb[(i + 3) & 3] = *(const v4f*)(x0 + DHID + dn);
    }
    vs += sa[i & 3];
    vs += sb[i & 3];
  }
  vs += ta; vs += tb;
  float s = vs.x + vs.y + vs.z + vs.w + pad[tid];
  asm volatile("" :: "v"(s));                      // keep loads live
}

// ---------------------------------------------------------------------------
// probe_B: ideal stream — wave reads 1 KB contiguous per instruction,
// grid-stride over all of x. Same grid (512x256). Writes nothing.
// ---------------------------------------------------------------------------
__global__ void probe_stream(const float* __restrict__ x) {
  const size_t n4  = (size_t)16384 * DHID / 4;     // 3,211,264 float4
  const size_t idx = (size_t)blockIdx.x * 256 + threadIdx.x;
  v4f vs = (v4f)0.f;
#pragma unroll
  for (int i = 0; i < 25; ++i) {
    const size_t j = idx + (size_t)i * 131072;
    if (j < n4) vs += ((const v4f*)x)[j];
  }
  float s = vs.x + vs.y + vs.z + vs.w;
  asm volatile("" :: "v"(s));
}

// ---------------------------------------------------------------------------
extern "C" void kernel_launch(void* const* d_in, const int* in_sizes, int n_in,
                              void* d_out, int out_size, void* d_ws, size_t ws_size,
                              hipStream_t stream) {
  const float* x     = (const float*)d_in[0];
  const float* W_in  = (const float*)d_in[1];
  const float* b_in  = (const float*)d_in[2];
  const float* W_ph  = (const float*)d_in[3];
  const float* b_ph  = (const float*)d_in[4];
  const float* W_out = (const float*)d_in[5];
  const float* b_out = (const float*)d_in[6];
  float* out = (float*)d_out;
  float* ws  = (float*)d_ws;

  // dur9 = ovh(5.78) + prep + main_G(cold) + probe_A + probe_B
  //      ≈ 23.9 + pA + pB  ->  {40: both fast | 47: pattern slow | 54: both slow}
  prep_kernel<<<(DHID + 64 + 1 + 3) / 4, 256, 0, stream>>>(W_in, b_in, W_ph, b_ph,
                                                           W_out, b_out, ws);
  main_kernel_G<<<512, 256, 0, stream>>>(x, ws, out);
  probe_pattern<<<512, 256, 0, stream>>>(x);
  probe_stream<<<512, 256, 0, stream>>>(x);
}